// Round 1
// 49.059 us; speedup vs baseline: 1.2042x; 1.2042x over previous
//
#include <hip/hip_runtime.h>

// Batched gather-GEMV:
//   out[bp, d] = (sum_h hs[bp, h] * W[props[bp], h, d] + bias[props[bp], d]) * mask[bp]
// B*P = 65536, H = 512, D = 2, NPROP = 10000.
//
// v2: property-bucketed schedule. The old per-(b,p) kernel fetched each
// prop's 4 KiB W matrix ~6.55x (65536 draws over 10000 props) -> ~390 MiB
// of traffic at the HBM ceiling. Here we bucket bp-pairs by prop (one
// atomic-scatter pass, no sort), then ONE WAVE PER PROP loads W once into
// 16 VGPRs and iterates its bucket, streaming only the 2 KiB hs row per
// entry. Traffic: 128 MiB (hs) + 40 MiB (W once) ~= 170 MiB.

#define H 512
#define D 2
#define CAP 48           // slots per property; Poisson(6.55) => P(count>48) ~ 0
#define OVF_WAVES 256    // cleanup waves for (theoretical) bucket overflow

// ---------------------------------------------------------------------------
// Shared per-bp GEMV body (old kernel's verified layout):
//   lane i, chunk k: W4[prop*256 + 64k + i] packs (W[h,0],W[h,1],W[h+1,0],W[h+1,1])
//                    hs2[bp*256  + 64k + i] packs (hs[h], hs[h+1]),  h = 128k + 2i
// ---------------------------------------------------------------------------
__device__ __forceinline__ void gemv_one_bp(
    const float* __restrict__ hs, const float* __restrict__ mask,
    const float* __restrict__ W,  const float* __restrict__ bias,
    float* __restrict__ out, int bp, int prop, int lane)
{
    const float2* h2 = (const float2*)(hs + (size_t)bp * H);
    const float4* w4 = (const float4*)(W + (size_t)prop * (H * D));

    float2 ha = h2[lane];
    float2 hb = h2[64 + lane];
    float2 hc = h2[128 + lane];
    float2 hd = h2[192 + lane];
    float4 wa = w4[lane];
    float4 wb = w4[64 + lane];
    float4 wc = w4[128 + lane];
    float4 wd = w4[192 + lane];

    float s0 = ha.x * wa.x + ha.y * wa.z
             + hb.x * wb.x + hb.y * wb.z
             + hc.x * wc.x + hc.y * wc.z
             + hd.x * wd.x + hd.y * wd.z;
    float s1 = ha.x * wa.y + ha.y * wa.w
             + hb.x * wb.y + hb.y * wb.w
             + hc.x * wc.y + hc.y * wc.w
             + hd.x * wd.y + hd.y * wd.w;

    #pragma unroll
    for (int off = 32; off > 0; off >>= 1) {
        s0 += __shfl_xor(s0, off, 64);
        s1 += __shfl_xor(s1, off, 64);
    }

    if (lane == 0) {
        const float m  = mask[bp];
        const float b0 = bias[(size_t)prop * D + 0];
        const float b1 = bias[(size_t)prop * D + 1];
        float2 r;
        r.x = (s0 + b0) * m;
        r.y = (s1 + b1) * m;
        *(float2*)(out + (size_t)bp * D) = r;
    }
}

// ---------------------------------------------------------------------------
// Kernel 1: bucket bp-pairs by property (count + fixed-cap scatter, one pass)
// ---------------------------------------------------------------------------
__global__ __launch_bounds__(256) void bucket_kernel(
    const int* __restrict__ props, int BP,
    int* __restrict__ counts,   // [nprop], pre-zeroed
    int* __restrict__ slots,    // [nprop * CAP]
    int* __restrict__ ovf_cnt,  // [1], pre-zeroed
    int* __restrict__ ovf)      // [BP]
{
    int i = blockIdx.x * blockDim.x + threadIdx.x;
    const int stride = gridDim.x * blockDim.x;
    for (; i < BP; i += stride) {
        const int p = props[i];
        const int idx = atomicAdd(&counts[p], 1);
        if (idx < CAP) {
            slots[p * CAP + idx] = i;
        } else {
            const int o = atomicAdd(ovf_cnt, 1);
            ovf[o] = i;
        }
    }
}

// ---------------------------------------------------------------------------
// Kernel 2: one wave per property. Load W once into regs, iterate bucket.
// Waves [nprop, nprop+OVF_WAVES) grid-stride the overflow list (old path).
// ---------------------------------------------------------------------------
__global__ __launch_bounds__(256) void per_prop_kernel(
    const float* __restrict__ hs,
    const int*   __restrict__ props,
    const float* __restrict__ mask,
    const float* __restrict__ W,
    const float* __restrict__ bias,
    float*       __restrict__ out,
    const int*   __restrict__ counts,
    const int*   __restrict__ slots,
    const int*   __restrict__ ovf_cnt,
    const int*   __restrict__ ovf,
    int nprop)
{
    const int wid  = (blockIdx.x * blockDim.x + threadIdx.x) >> 6;
    const int lane = threadIdx.x & 63;

    if (wid < nprop) {
        int cnt = counts[wid];
        if (cnt > CAP) cnt = CAP;
        if (cnt == 0) return;

        // W for this property, resident in 16 VGPRs for the whole bucket.
        const float4* w4 = (const float4*)(W + (size_t)wid * (H * D));
        const float4 wa = w4[lane];
        const float4 wb = w4[64 + lane];
        const float4 wc = w4[128 + lane];
        const float4 wd = w4[192 + lane];
        const float b0 = bias[(size_t)wid * D + 0];
        const float b1 = bias[(size_t)wid * D + 1];

        // Bucket's bp list: one entry per lane, broadcast via dynamic shfl.
        const int myslot = (lane < cnt) ? slots[wid * CAP + lane] : 0;

        // Software pipeline: prefetch hs row j+1 while reducing row j.
        int bp = __shfl(myslot, 0, 64);
        const float2* h2 = (const float2*)(hs + (size_t)bp * H);
        float2 ha = h2[lane];
        float2 hb = h2[64 + lane];
        float2 hc = h2[128 + lane];
        float2 hd = h2[192 + lane];

        for (int j = 0; j < cnt; ++j) {
            const int bpn = __shfl(myslot, (j + 1 < 64) ? j + 1 : 0, 64);
            float2 na = make_float2(0.f, 0.f), nb = na, nc = na, nd = na;
            if (j + 1 < cnt) {
                const float2* hn = (const float2*)(hs + (size_t)bpn * H);
                na = hn[lane];
                nb = hn[64 + lane];
                nc = hn[128 + lane];
                nd = hn[192 + lane];
            }

            float s0 = ha.x * wa.x + ha.y * wa.z
                     + hb.x * wb.x + hb.y * wb.z
                     + hc.x * wc.x + hc.y * wc.z
                     + hd.x * wd.x + hd.y * wd.z;
            float s1 = ha.x * wa.y + ha.y * wa.w
                     + hb.x * wb.y + hb.y * wb.w
                     + hc.x * wc.y + hc.y * wc.w
                     + hd.x * wd.y + hd.y * wd.w;

            #pragma unroll
            for (int off = 32; off > 0; off >>= 1) {
                s0 += __shfl_xor(s0, off, 64);
                s1 += __shfl_xor(s1, off, 64);
            }

            if (lane == 0) {
                const float m = mask[bp];
                float2 r;
                r.x = (s0 + b0) * m;
                r.y = (s1 + b1) * m;
                *(float2*)(out + (size_t)bp * D) = r;
            }

            bp = bpn;
            ha = na; hb = nb; hc = nc; hd = nd;
        }
    } else {
        // Overflow cleanup (normally empty: bucket > CAP has ~zero probability).
        const int n = *ovf_cnt;
        for (int i = wid - nprop; i < n; i += OVF_WAVES) {
            const int bp = ovf[i];
            gemv_one_bp(hs, mask, W, bias, out, bp, props[bp], lane);
        }
    }
}

// ---------------------------------------------------------------------------
// Fallback: original per-bp kernel (used only if workspace is too small).
// ---------------------------------------------------------------------------
__global__ __launch_bounds__(256) void adapter_gemv_kernel(
    const float* __restrict__ hs,
    const int*   __restrict__ props,
    const float* __restrict__ mask,
    const float* __restrict__ W,
    const float* __restrict__ bias,
    float* __restrict__ out,
    int BP)
{
    const int tid  = blockIdx.x * blockDim.x + threadIdx.x;
    const int bp   = tid >> 6;
    const int lane = tid & 63;
    if (bp >= BP) return;
    gemv_one_bp(hs, mask, W, bias, out, bp, props[bp], lane);
}

extern "C" void kernel_launch(void* const* d_in, const int* in_sizes, int n_in,
                              void* d_out, int out_size, void* d_ws, size_t ws_size,
                              hipStream_t stream) {
    const float* hs    = (const float*)d_in[0];
    const int*   props = (const int*)d_in[1];
    const float* mask  = (const float*)d_in[2];
    const float* W     = (const float*)d_in[3];
    const float* bias  = (const float*)d_in[4];
    float* out = (float*)d_out;

    const int BP    = in_sizes[1];                 // 512 * 128 = 65536 pairs
    const int nprop = in_sizes[3] / (H * D);       // 10000

    // Workspace layout (all int32):
    //   [0, nprop)                : counts
    //   [nprop]                   : ovf_cnt
    //   slots at 256B-aligned off : nprop * CAP
    //   ovf   after slots         : BP
    const size_t off_counts = 0;
    const size_t off_slots  = (((size_t)nprop * 4 + 4) + 255) & ~(size_t)255;
    const size_t off_ovf    = off_slots + (size_t)nprop * CAP * 4;
    const size_t ws_needed  = off_ovf + (size_t)BP * 4;

    if (ws_size < ws_needed) {
        // Not enough workspace: original verified path.
        const int threads = 256;
        const int blocks  = (BP * 64 + threads - 1) / threads;
        adapter_gemv_kernel<<<blocks, threads, 0, stream>>>(hs, props, mask, W, bias, out, BP);
        return;
    }

    int* counts  = (int*)((char*)d_ws + off_counts);
    int* ovf_cnt = counts + nprop;
    int* slots   = (int*)((char*)d_ws + off_slots);
    int* ovf     = (int*)((char*)d_ws + off_ovf);

    // Zero counts + ovf_cnt (graph-capture-safe stream op).
    hipMemsetAsync(counts, 0, off_slots, stream);

    {   // bucket
        const int threads = 256;
        int blocks = (BP + threads - 1) / threads;
        if (blocks > 1024) blocks = 1024;
        bucket_kernel<<<blocks, threads, 0, stream>>>(props, BP, counts, slots, ovf_cnt, ovf);
    }

    {   // per-prop gemv (+ overflow cleanup waves)
        const int threads     = 256;
        const int total_waves = nprop + OVF_WAVES;
        const int blocks      = (total_waves * 64 + threads - 1) / threads;
        per_prop_kernel<<<blocks, threads, 0, stream>>>(
            hs, props, mask, W, bias, out, counts, slots, ovf_cnt, ovf, nprop);
    }
}

// Round 2
// 44.207 us; speedup vs baseline: 1.3364x; 1.1098x over previous
//
#include <hip/hip_runtime.h>

// Batched gather-GEMV:
//   out[bp, d] = (sum_h hs[bp, h] * W[props[bp], h, d] + bias[props[bp], d]) * mask[bp]
// B*P = 65536, H = 512, D = 2, NPROP = 10000.
//
// v3: property-bucketed schedule, 4-way bucket split.
// v2 (one wave per prop, serial over ~6.5 bucket entries) deduped W traffic
// (FETCH 390->88 MB) but became latency-bound: 1.15 TB/s, VALUBusy 5%,
// only 10K waves each with a serial load->12-shfl chain. v3 keeps the
// W-dedup but splits each bucket over 4 WAVES IN ONE BLOCK (block = prop,
// wave k takes entries k, k+4, ...): 4x the waves, 1/4 the serial chain,
// and the 4 redundant W loads are same-block -> L1/L2 hits, so HBM W
// traffic stays ~40 MB.

#define H 512
#define D 2
#define CAP 48           // slots per property; Poisson(6.55) => P(count>48) ~ 0
#define KSPLIT 4         // waves per property (one block)
#define OVF_BLOCKS 64    // cleanup blocks for (theoretical) bucket overflow

// ---------------------------------------------------------------------------
// Shared per-bp GEMV body (verified layout):
//   lane i, chunk k: W4[prop*256 + 64k + i] packs (W[h,0],W[h,1],W[h+1,0],W[h+1,1])
//                    hs2[bp*256  + 64k + i] packs (hs[h], hs[h+1]),  h = 128k + 2i
// ---------------------------------------------------------------------------
__device__ __forceinline__ void gemv_one_bp(
    const float* __restrict__ hs, const float* __restrict__ mask,
    const float* __restrict__ W,  const float* __restrict__ bias,
    float* __restrict__ out, int bp, int prop, int lane)
{
    const float2* h2 = (const float2*)(hs + (size_t)bp * H);
    const float4* w4 = (const float4*)(W + (size_t)prop * (H * D));

    float2 ha = h2[lane];
    float2 hb = h2[64 + lane];
    float2 hc = h2[128 + lane];
    float2 hd = h2[192 + lane];
    float4 wa = w4[lane];
    float4 wb = w4[64 + lane];
    float4 wc = w4[128 + lane];
    float4 wd = w4[192 + lane];

    float s0 = ha.x * wa.x + ha.y * wa.z
             + hb.x * wb.x + hb.y * wb.z
             + hc.x * wc.x + hc.y * wc.z
             + hd.x * wd.x + hd.y * wd.z;
    float s1 = ha.x * wa.y + ha.y * wa.w
             + hb.x * wb.y + hb.y * wb.w
             + hc.x * wc.y + hc.y * wc.w
             + hd.x * wd.y + hd.y * wd.w;

    #pragma unroll
    for (int off = 32; off > 0; off >>= 1) {
        s0 += __shfl_xor(s0, off, 64);
        s1 += __shfl_xor(s1, off, 64);
    }

    if (lane == 0) {
        const float m  = mask[bp];
        const float b0 = bias[(size_t)prop * D + 0];
        const float b1 = bias[(size_t)prop * D + 1];
        float2 r;
        r.x = (s0 + b0) * m;
        r.y = (s1 + b1) * m;
        *(float2*)(out + (size_t)bp * D) = r;
    }
}

// ---------------------------------------------------------------------------
// Kernel 1: bucket bp-pairs by property (count + fixed-cap scatter, one pass)
// ---------------------------------------------------------------------------
__global__ __launch_bounds__(256) void bucket_kernel(
    const int* __restrict__ props, int BP,
    int* __restrict__ counts,   // [nprop], pre-zeroed
    int* __restrict__ slots,    // [nprop * CAP]
    int* __restrict__ ovf_cnt,  // [1], pre-zeroed
    int* __restrict__ ovf)      // [BP]
{
    int i = blockIdx.x * blockDim.x + threadIdx.x;
    const int stride = gridDim.x * blockDim.x;
    for (; i < BP; i += stride) {
        const int p = props[i];
        const int idx = atomicAdd(&counts[p], 1);
        if (idx < CAP) {
            slots[p * CAP + idx] = i;
        } else {
            const int o = atomicAdd(ovf_cnt, 1);
            ovf[o] = i;
        }
    }
}

// ---------------------------------------------------------------------------
// Kernel 2: one BLOCK per property, 4 waves split the bucket (stride-4).
// Wave k of block p handles entries k, k+KSPLIT, k+2*KSPLIT, ...
// All 4 waves load the same 4 KiB W -> first from HBM/L2, rest L1 hits.
// Blocks [nprop, nprop+OVF_BLOCKS) grid-stride the overflow list (old path).
// ---------------------------------------------------------------------------
__global__ __launch_bounds__(256) void per_prop_kernel(
    const float* __restrict__ hs,
    const int*   __restrict__ props,
    const float* __restrict__ mask,
    const float* __restrict__ W,
    const float* __restrict__ bias,
    float*       __restrict__ out,
    const int*   __restrict__ counts,
    const int*   __restrict__ slots,
    const int*   __restrict__ ovf_cnt,
    const int*   __restrict__ ovf,
    int nprop)
{
    const int k    = threadIdx.x >> 6;   // sub-wave 0..3
    const int lane = threadIdx.x & 63;

    if (blockIdx.x < nprop) {
        const int p = blockIdx.x;
        int cnt = counts[p];
        if (cnt > CAP) cnt = CAP;
        if (k >= cnt) return;                       // this wave has no entries
        const int nt = (cnt - k + KSPLIT - 1) / KSPLIT;   // my entry count

        // W for this property, resident in 16 VGPRs.
        const float4* w4 = (const float4*)(W + (size_t)p * (H * D));
        const float4 wa = w4[lane];
        const float4 wb = w4[64 + lane];
        const float4 wc = w4[128 + lane];
        const float4 wd = w4[192 + lane];
        const float b0 = bias[(size_t)p * D + 0];
        const float b1 = bias[(size_t)p * D + 1];

        // lane t holds the slot for my t-th entry (k + KSPLIT*t); max nt = 12.
        const int myslot = (lane < nt) ? slots[p * CAP + k + KSPLIT * lane] : 0;

        // Software pipeline: prefetch hs row t+1 while reducing row t.
        int bp = __shfl(myslot, 0, 64);
        const float2* h2 = (const float2*)(hs + (size_t)bp * H);
        float2 ha = h2[lane];
        float2 hb = h2[64 + lane];
        float2 hc = h2[128 + lane];
        float2 hd = h2[192 + lane];

        for (int t = 0; t < nt; ++t) {
            const int bpn = __shfl(myslot, (t + 1 < 64) ? t + 1 : 0, 64);
            float2 na = make_float2(0.f, 0.f), nb = na, nc = na, nd = na;
            if (t + 1 < nt) {
                const float2* hn = (const float2*)(hs + (size_t)bpn * H);
                na = hn[lane];
                nb = hn[64 + lane];
                nc = hn[128 + lane];
                nd = hn[192 + lane];
            }

            float s0 = ha.x * wa.x + ha.y * wa.z
                     + hb.x * wb.x + hb.y * wb.z
                     + hc.x * wc.x + hc.y * wc.z
                     + hd.x * wd.x + hd.y * wd.z;
            float s1 = ha.x * wa.y + ha.y * wa.w
                     + hb.x * wb.y + hb.y * wb.w
                     + hc.x * wc.y + hc.y * wc.w
                     + hd.x * wd.y + hd.y * wd.w;

            #pragma unroll
            for (int off = 32; off > 0; off >>= 1) {
                s0 += __shfl_xor(s0, off, 64);
                s1 += __shfl_xor(s1, off, 64);
            }

            if (lane == 0) {
                const float m = mask[bp];
                float2 r;
                r.x = (s0 + b0) * m;
                r.y = (s1 + b1) * m;
                *(float2*)(out + (size_t)bp * D) = r;
            }

            bp = bpn;
            ha = na; hb = nb; hc = nc; hd = nd;
        }
    } else {
        // Overflow cleanup (normally empty: bucket > CAP has ~zero probability).
        const int w = (blockIdx.x - nprop) * KSPLIT + k;
        const int n = *ovf_cnt;
        for (int i = w; i < n; i += OVF_BLOCKS * KSPLIT) {
            const int bp = ovf[i];
            gemv_one_bp(hs, mask, W, bias, out, bp, props[bp], lane);
        }
    }
}

// ---------------------------------------------------------------------------
// Fallback: original per-bp kernel (used only if workspace is too small).
// ---------------------------------------------------------------------------
__global__ __launch_bounds__(256) void adapter_gemv_kernel(
    const float* __restrict__ hs,
    const int*   __restrict__ props,
    const float* __restrict__ mask,
    const float* __restrict__ W,
    const float* __restrict__ bias,
    float* __restrict__ out,
    int BP)
{
    const int tid  = blockIdx.x * blockDim.x + threadIdx.x;
    const int bp   = tid >> 6;
    const int lane = tid & 63;
    if (bp >= BP) return;
    gemv_one_bp(hs, mask, W, bias, out, bp, props[bp], lane);
}

extern "C" void kernel_launch(void* const* d_in, const int* in_sizes, int n_in,
                              void* d_out, int out_size, void* d_ws, size_t ws_size,
                              hipStream_t stream) {
    const float* hs    = (const float*)d_in[0];
    const int*   props = (const int*)d_in[1];
    const float* mask  = (const float*)d_in[2];
    const float* W     = (const float*)d_in[3];
    const float* bias  = (const float*)d_in[4];
    float* out = (float*)d_out;

    const int BP    = in_sizes[1];                 // 512 * 128 = 65536 pairs
    const int nprop = in_sizes[3] / (H * D);       // 10000

    // Workspace layout (all int32):
    //   [0, nprop)                : counts
    //   [nprop]                   : ovf_cnt
    //   slots at 256B-aligned off : nprop * CAP
    //   ovf   after slots         : BP
    const size_t off_counts = 0;
    const size_t off_slots  = (((size_t)nprop * 4 + 4) + 255) & ~(size_t)255;
    const size_t off_ovf    = off_slots + (size_t)nprop * CAP * 4;
    const size_t ws_needed  = off_ovf + (size_t)BP * 4;

    if (ws_size < ws_needed) {
        // Not enough workspace: original verified path.
        const int threads = 256;
        const int blocks  = (BP * 64 + threads - 1) / threads;
        adapter_gemv_kernel<<<blocks, threads, 0, stream>>>(hs, props, mask, W, bias, out, BP);
        return;
    }

    int* counts  = (int*)((char*)d_ws + off_counts);
    int* ovf_cnt = counts + nprop;
    int* slots   = (int*)((char*)d_ws + off_slots);
    int* ovf     = (int*)((char*)d_ws + off_ovf);

    // Zero counts + ovf_cnt (graph-capture-safe stream op).
    hipMemsetAsync(counts, 0, off_slots, stream);

    {   // bucket
        const int threads = 256;
        int blocks = (BP + threads - 1) / threads;
        if (blocks > 1024) blocks = 1024;
        bucket_kernel<<<blocks, threads, 0, stream>>>(props, BP, counts, slots, ovf_cnt, ovf);
    }

    {   // per-prop gemv: one block per prop + overflow blocks
        const int threads = 256;
        const int blocks  = nprop + OVF_BLOCKS;
        per_prop_kernel<<<blocks, threads, 0, stream>>>(
            hs, props, mask, W, bias, out, counts, slots, ovf_cnt, ovf, nprop);
    }
}

// Round 3
// 43.215 us; speedup vs baseline: 1.3671x; 1.0229x over previous
//
#include <hip/hip_runtime.h>

// Batched gather-GEMV:
//   out[bp, d] = (sum_h hs[bp, h] * W[props[bp], h, d] + bias[props[bp], d]) * mask[bp]
// B*P = 65536, H = 512, D = 2, NPROP = 10000.
//
// v4: v3 (property-bucketed, 4-wave bucket split, W-in-registers) with a
// PAIRED reduction: two bucket entries reduced jointly in 7 shfls
// (vs 2x12 for separate 64-lane butterflies). After the FMAs each lane
// holds (s0A, s1A, s0B, s1B); offset-1 exchange folds s0/s1 into lane
// bit0 classes, offset-2 folds A/B into bit1 classes, then a 4-step
// butterfly (4,8,16,32) reduces all four dot products at once. Lanes 0-3
// hold the four outputs and store directly.

#define H 512
#define D 2
#define CAP 48           // slots per property; Poisson(6.55) => P(count>48) ~ 0
#define KSPLIT 4         // waves per property (one block)
#define OVF_BLOCKS 64    // cleanup blocks for (theoretical) bucket overflow

// ---------------------------------------------------------------------------
// Shared per-bp GEMV body (verified layout), for overflow/fallback paths:
//   lane i, chunk k: W4[prop*256 + 64k + i] packs (W[h,0],W[h,1],W[h+1,0],W[h+1,1])
//                    hs2[bp*256  + 64k + i] packs (hs[h], hs[h+1]),  h = 128k + 2i
// ---------------------------------------------------------------------------
__device__ __forceinline__ void gemv_one_bp(
    const float* __restrict__ hs, const float* __restrict__ mask,
    const float* __restrict__ W,  const float* __restrict__ bias,
    float* __restrict__ out, int bp, int prop, int lane)
{
    const float2* h2 = (const float2*)(hs + (size_t)bp * H);
    const float4* w4 = (const float4*)(W + (size_t)prop * (H * D));

    float2 ha = h2[lane];
    float2 hb = h2[64 + lane];
    float2 hc = h2[128 + lane];
    float2 hd = h2[192 + lane];
    float4 wa = w4[lane];
    float4 wb = w4[64 + lane];
    float4 wc = w4[128 + lane];
    float4 wd = w4[192 + lane];

    float s0 = ha.x * wa.x + ha.y * wa.z
             + hb.x * wb.x + hb.y * wb.z
             + hc.x * wc.x + hc.y * wc.z
             + hd.x * wd.x + hd.y * wd.z;
    float s1 = ha.x * wa.y + ha.y * wa.w
             + hb.x * wb.y + hb.y * wb.w
             + hc.x * wc.y + hc.y * wc.w
             + hd.x * wd.y + hd.y * wd.w;

    #pragma unroll
    for (int off = 32; off > 0; off >>= 1) {
        s0 += __shfl_xor(s0, off, 64);
        s1 += __shfl_xor(s1, off, 64);
    }

    if (lane == 0) {
        const float m  = mask[bp];
        const float b0 = bias[(size_t)prop * D + 0];
        const float b1 = bias[(size_t)prop * D + 1];
        float2 r;
        r.x = (s0 + b0) * m;
        r.y = (s1 + b1) * m;
        *(float2*)(out + (size_t)bp * D) = r;
    }
}

// ---------------------------------------------------------------------------
// Kernel 1: bucket bp-pairs by property (count + fixed-cap scatter, one pass)
// ---------------------------------------------------------------------------
__global__ __launch_bounds__(256) void bucket_kernel(
    const int* __restrict__ props, int BP,
    int* __restrict__ counts,   // [nprop], pre-zeroed
    int* __restrict__ slots,    // [nprop * CAP]
    int* __restrict__ ovf_cnt,  // [1], pre-zeroed
    int* __restrict__ ovf)      // [BP]
{
    int i = blockIdx.x * blockDim.x + threadIdx.x;
    const int stride = gridDim.x * blockDim.x;
    for (; i < BP; i += stride) {
        const int p = props[i];
        const int idx = atomicAdd(&counts[p], 1);
        if (idx < CAP) {
            slots[p * CAP + idx] = i;
        } else {
            const int o = atomicAdd(ovf_cnt, 1);
            ovf[o] = i;
        }
    }
}

// ---------------------------------------------------------------------------
// Kernel 2: one BLOCK per property, 4 waves split the bucket (stride-4),
// entries processed in PAIRS with a joint 7-shfl reduction.
// Blocks [nprop, nprop+OVF_BLOCKS) grid-stride the overflow list (old path).
// ---------------------------------------------------------------------------
__global__ __launch_bounds__(256) void per_prop_kernel(
    const float* __restrict__ hs,
    const int*   __restrict__ props,
    const float* __restrict__ mask,
    const float* __restrict__ W,
    const float* __restrict__ bias,
    float*       __restrict__ out,
    const int*   __restrict__ counts,
    const int*   __restrict__ slots,
    const int*   __restrict__ ovf_cnt,
    const int*   __restrict__ ovf,
    int nprop)
{
    const int k    = threadIdx.x >> 6;   // sub-wave 0..3
    const int lane = threadIdx.x & 63;

    if (blockIdx.x < nprop) {
        const int p = blockIdx.x;
        int cnt = counts[p];
        if (cnt > CAP) cnt = CAP;
        if (k >= cnt) return;                       // this wave has no entries
        const int nt = (cnt - k + KSPLIT - 1) / KSPLIT;   // my entry count (<=12)

        // W for this property, resident in 16 VGPRs for the whole bucket.
        const float4* w4 = (const float4*)(W + (size_t)p * (H * D));
        const float4 wa = w4[lane];
        const float4 wb = w4[64 + lane];
        const float4 wc = w4[128 + lane];
        const float4 wd = w4[192 + lane];
        const float b0 = bias[(size_t)p * D + 0];
        const float b1 = bias[(size_t)p * D + 1];
        const float bsel = (lane & 1) ? b1 : b0;

        // lane t holds the slot for my t-th entry (k + KSPLIT*t); max nt = 12.
        const int myslot = (lane < nt) ? slots[p * CAP + k + KSPLIT * lane] : 0;

        for (int u = 0; u < nt; u += 2) {
            const int  bpA  = __shfl(myslot, u, 64);
            const bool hasB = (u + 1 < nt);
            const int  bpB  = __shfl(myslot, hasB ? (u + 1) : u, 64);

            // Load both hs rows (8 lane-contiguous float2 loads, issued together).
            const float2* hA = (const float2*)(hs + (size_t)bpA * H);
            float2 a0 = hA[lane];
            float2 a1 = hA[64 + lane];
            float2 a2 = hA[128 + lane];
            float2 a3 = hA[192 + lane];
            float2 c0, c1, c2, c3;
            if (hasB) {
                const float2* hB = (const float2*)(hs + (size_t)bpB * H);
                c0 = hB[lane];
                c1 = hB[64 + lane];
                c2 = hB[128 + lane];
                c3 = hB[192 + lane];
            } else {
                c0 = c1 = c2 = c3 = make_float2(0.f, 0.f);
            }

            // Per-lane partials for both entries.
            float s0A = a0.x * wa.x + a0.y * wa.z
                      + a1.x * wb.x + a1.y * wb.z
                      + a2.x * wc.x + a2.y * wc.z
                      + a3.x * wd.x + a3.y * wd.z;
            float s1A = a0.x * wa.y + a0.y * wa.w
                      + a1.x * wb.y + a1.y * wb.w
                      + a2.x * wc.y + a2.y * wc.w
                      + a3.x * wd.y + a3.y * wd.w;
            float s0B = c0.x * wa.x + c0.y * wa.z
                      + c1.x * wb.x + c1.y * wb.z
                      + c2.x * wc.x + c2.y * wc.z
                      + c3.x * wd.x + c3.y * wd.z;
            float s1B = c0.x * wa.y + c0.y * wa.w
                      + c1.x * wb.y + c1.y * wb.w
                      + c2.x * wc.y + c2.y * wc.w
                      + c3.x * wd.y + c3.y * wd.w;

            // Joint reduction: 7 shfls for all four dot products.
            // Step 1 (offset 1): fold s0/s1 into lane bit0 classes.
            const bool o1 = (lane & 1) != 0;
            float keepA = o1 ? s1A : s0A;
            float sendA = o1 ? s0A : s1A;
            float vA = keepA + __shfl_xor(sendA, 1, 64);
            float keepB = o1 ? s1B : s0B;
            float sendB = o1 ? s0B : s1B;
            float vB = keepB + __shfl_xor(sendB, 1, 64);
            // Step 2 (offset 2): fold A/B into lane bit1 classes.
            const bool o2 = (lane & 2) != 0;
            float keep = o2 ? vB : vA;
            float send = o2 ? vA : vB;
            float w = keep + __shfl_xor(send, 2, 64);
            // Steps 3-6: butterfly over remaining lanes, class-preserving.
            #pragma unroll
            for (int off = 4; off <= 32; off <<= 1)
                w += __shfl_xor(w, off, 64);

            // lane 0: s0A, lane 1: s1A, lane 2: s0B, lane 3: s1B.
            if (lane < (hasB ? 4 : 2)) {
                const int bps = (lane & 2) ? bpB : bpA;
                const float m = mask[bps];
                out[(size_t)bps * D + (lane & 1)] = (w + bsel) * m;
            }
        }
    } else {
        // Overflow cleanup (normally empty: bucket > CAP has ~zero probability).
        const int wv = (blockIdx.x - nprop) * KSPLIT + k;
        const int n = *ovf_cnt;
        for (int i = wv; i < n; i += OVF_BLOCKS * KSPLIT) {
            const int bp = ovf[i];
            gemv_one_bp(hs, mask, W, bias, out, bp, props[bp], lane);
        }
    }
}

// ---------------------------------------------------------------------------
// Fallback: original per-bp kernel (used only if workspace is too small).
// ---------------------------------------------------------------------------
__global__ __launch_bounds__(256) void adapter_gemv_kernel(
    const float* __restrict__ hs,
    const int*   __restrict__ props,
    const float* __restrict__ mask,
    const float* __restrict__ W,
    const float* __restrict__ bias,
    float* __restrict__ out,
    int BP)
{
    const int tid  = blockIdx.x * blockDim.x + threadIdx.x;
    const int bp   = tid >> 6;
    const int lane = tid & 63;
    if (bp >= BP) return;
    gemv_one_bp(hs, mask, W, bias, out, bp, props[bp], lane);
}

extern "C" void kernel_launch(void* const* d_in, const int* in_sizes, int n_in,
                              void* d_out, int out_size, void* d_ws, size_t ws_size,
                              hipStream_t stream) {
    const float* hs    = (const float*)d_in[0];
    const int*   props = (const int*)d_in[1];
    const float* mask  = (const float*)d_in[2];
    const float* W     = (const float*)d_in[3];
    const float* bias  = (const float*)d_in[4];
    float* out = (float*)d_out;

    const int BP    = in_sizes[1];                 // 512 * 128 = 65536 pairs
    const int nprop = in_sizes[3] / (H * D);       // 10000

    // Workspace layout (all int32):
    //   [0, nprop)                : counts
    //   [nprop]                   : ovf_cnt
    //   slots at 256B-aligned off : nprop * CAP
    //   ovf   after slots         : BP
    const size_t off_counts = 0;
    const size_t off_slots  = (((size_t)nprop * 4 + 4) + 255) & ~(size_t)255;
    const size_t off_ovf    = off_slots + (size_t)nprop * CAP * 4;
    const size_t ws_needed  = off_ovf + (size_t)BP * 4;

    if (ws_size < ws_needed) {
        // Not enough workspace: original verified path.
        const int threads = 256;
        const int blocks  = (BP * 64 + threads - 1) / threads;
        adapter_gemv_kernel<<<blocks, threads, 0, stream>>>(hs, props, mask, W, bias, out, BP);
        return;
    }

    int* counts  = (int*)((char*)d_ws + off_counts);
    int* ovf_cnt = counts + nprop;
    int* slots   = (int*)((char*)d_ws + off_slots);
    int* ovf     = (int*)((char*)d_ws + off_ovf);

    // Zero counts + ovf_cnt (graph-capture-safe stream op).
    hipMemsetAsync(counts, 0, off_slots, stream);

    {   // bucket
        const int threads = 256;
        int blocks = (BP + threads - 1) / threads;
        if (blocks > 1024) blocks = 1024;
        bucket_kernel<<<blocks, threads, 0, stream>>>(props, BP, counts, slots, ovf_cnt, ovf);
    }

    {   // per-prop gemv: one block per prop + overflow blocks
        const int threads = 256;
        const int blocks  = nprop + OVF_BLOCKS;
        per_prop_kernel<<<blocks, threads, 0, stream>>>(
            hs, props, mask, W, bias, out, counts, slots, ovf_cnt, ovf, nprop);
    }
}